// Round 8
// baseline (275.456 us; speedup 1.0000x reference)
//
#include <hip/hip_runtime.h>

#define BB 4
#define NT 256
#define NZ 384
#define NX 384
#define NREC 128
#define NZX (NZ*NX)        // 147456
#define BNZX (BB*NZX)      // 589824
#define DT 0.001f
#define INV_DH2 0.01f      // 1/(10*10)

#define TILE 48            // interior tile edge
#define HALO 8             // halo width = steps per exchange
#define REGN 64            // TILE + 2*HALO
#define NBLK 256           // 8x8 tiles x 4 batches (1 block/CU)
#define NTHR 512           // 8 waves: wave w owns rows 8w..8w+7, lane = col
#define FSTRIDE 16         // flag spread (64 B) -> no line sharing

__global__ void wave_init(unsigned* flags) {
    int i = blockIdx.x * blockDim.x + threadIdx.x;
    if (i < NBLK * FSTRIDE) flags[i] = 0u;
}

__device__ inline float dpp_shl1(float v) {
    return __int_as_float(__builtin_amdgcn_update_dpp(
        0, __float_as_int(v), 0x130 /*WAVE_SHL1*/, 0xf, 0xf, true));
}
__device__ inline float dpp_shr1(float v) {
    return __int_as_float(__builtin_amdgcn_update_dpp(
        0, __float_as_int(v), 0x138 /*WAVE_SHR1*/, 0xf, 0xf, true));
}

// float2 {cur,prv} packed as u64, moved with agent-scope relaxed atomics
// (coherent at LLC -> no cache-maintenance ops, visible cross-XCD).
__device__ inline void stg2(unsigned long long* p, float a, float b) {
    unsigned long long v = (unsigned long long)__float_as_uint(a)
                         | ((unsigned long long)__float_as_uint(b) << 32);
    __hip_atomic_store(p, v, __ATOMIC_RELAXED, __HIP_MEMORY_SCOPE_AGENT);
}
__device__ inline unsigned long long ldg2(const unsigned long long* p) {
    return __hip_atomic_load(p, __ATOMIC_RELAXED, __HIP_MEMORY_SCOPE_AGENT);
}

__global__ __launch_bounds__(NTHR)
void wave_tiled(float* __restrict__ ws, const float* __restrict__ vp,
                const float* __restrict__ x,
                const int* __restrict__ src_y, const int* __restrict__ src_x,
                const int* __restrict__ rec_y, const int* __restrict__ rec_x,
                float* __restrict__ y) {
    __shared__ float bnd[2][16][REGN];   // [parity][2*wave+{top,bot}][col]
    __shared__ float recBuf[NREC][8];    // receiver samples per 8-step window
    __shared__ float xs[NT];
    __shared__ int recLoc[NREC], recOut[NREC];
    __shared__ int recCnt;

    unsigned* flags = (unsigned*)(ws + 4*BNZX);
    unsigned long long* F[2] = { (unsigned long long*)ws,
                                 (unsigned long long*)ws + BNZX };

    const int tid = threadIdx.x;
    const int col = tid & 63;
    const int w   = tid >> 6;
    const int r0  = w << 3;
    const int blk = blockIdx.x;
    const int b  = blk >> 6;
    const int tz = (blk >> 3) & 7;
    const int tx = blk & 7;
    const int oz = tz*TILE - HALO, ox = tx*TILE - HALO;
    const int gx = ox + col;
    const int sy = src_y[b], sx = src_x[b];

    if (tid == 0) recCnt = 0;
    for (int k = tid; k < 16*REGN; k += NTHR) ((float*)bnd[0])[k] = 0.f;
    for (int k = tid; k < NT; k += NTHR) xs[k] = x[b*NT + k];
    __syncthreads();
    for (int r = tid; r < NREC; r += NTHR) {
        int ry = rec_y[r], rx = rec_x[r];
        if (ry/TILE == tz && rx/TILE == tx) {
            int p = atomicAdd(&recCnt, 1);
            recLoc[p] = ((ry - oz) << 6) | (rx - ox);
            recOut[p] = b*NREC + r;
        }
    }
    __syncthreads();

    // per-thread receiver ownership cache (cap 4, LDS-loop fallback)
    int myN = 0, myM[4], myP[4];
    bool ovf = false;
    for (int p = 0; p < recCnt; ++p) {
        int rl = recLoc[p];
        if ((rl & 63) == col) {
            int rm = (rl >> 6) - r0;
            if ((unsigned)rm < 8u) {
                if (myN < 4) { myM[myN] = rm; myP[myN] = p; ++myN; }
                else ovf = true;
            }
        }
    }

    // neighbor ids for sync (lanes 0..7 of wave 0; other lanes poll self)
    int nbId = blk;
    if (tid < 8) {
        int d = tid + (tid >= 4);
        int nz2 = tz + d/3 - 1, nx2 = tx + d%3 - 1;
        if ((unsigned)nz2 < 8u && (unsigned)nx2 < 8u)
            nbId = (b << 6) | (nz2 << 3) | nx2;
    }

    float cur[8], prv[8], c2i[8];
    #pragma unroll
    for (int m = 0; m < 8; ++m) {
        cur[m] = 0.f; prv[m] = 0.f;
        const int gz = oz + r0 + m;
        const bool inner = (gz > 0 && gz < NZ-1 && gx > 0 && gx < NX-1);
        const float v = inner ? vp[gz*NX + gx] * DT : 0.f;
        c2i[m] = v * v * INV_DH2;    // 0 at edges -> lap auto-masked
    }
    const bool srcCol = (gx == sx);
    const int  srcM   = sy - oz - r0;
    const int  iuUp   = (2*w-1 < 0) ? 0 : 2*w-1;
    const int  iuDn   = (2*w+2 > 15) ? 15 : 2*w+2;
    // ring-load address/valid precompute (invariant over windows)
    const bool gxIn = (gx >= 0 && gx < NX);
    const int  gxc  = min(max(gx, 0), NX-1);
    __syncthreads();

    #pragma unroll 1
    for (int t = 0; t < NT; ++t) {
        const int pr = t & 1, pw = pr ^ 1;
        const float upB = bnd[pr][iuUp][col];
        const float dnB = bnd[pr][iuDn][col];

        float hn[8];
        #pragma unroll
        for (int m = 0; m < 8; ++m) {
            const float ce = cur[m];
            const float up = (m == 0) ? upB : cur[m-1];
            const float dn = (m == 7) ? dnB : cur[m+1];
            const float lf = dpp_shl1(ce);
            const float rt = dpp_shr1(ce);
            const float s  = (up + dn) + (lf + rt);
            hn[m] = fmaf(2.f, ce, -prv[m]) + c2i[m] * fmaf(-4.f, ce, s);
        }
        #pragma unroll
        for (int m = 0; m < 8; ++m) { prv[m] = cur[m]; cur[m] = hn[m]; }

        if (srcCol && (unsigned)srcM < 8u) {
            const float xv = xs[t];
            #pragma unroll
            for (int m = 0; m < 8; ++m) if (m == srcM) cur[m] += xv;
        }
        {   // receiver sampling -> LDS (no global ops in step loop)
            const int s2 = t & 7;
            if (ovf) {
                for (int p = 0; p < recCnt; ++p) {
                    int rl = recLoc[p];
                    if ((rl & 63) == col) {
                        int rm = (rl >> 6) - r0;
                        if ((unsigned)rm < 8u) {
                            float v = cur[0];
                            #pragma unroll
                            for (int m = 1; m < 8; ++m) if (rm == m) v = cur[m];
                            recBuf[p][s2] = v;
                        }
                    }
                }
            } else {
                #pragma unroll
                for (int k = 0; k < 4; ++k) {
                    if (k < myN) {
                        float v = cur[0];
                        #pragma unroll
                        for (int m = 1; m < 8; ++m) if (myM[k] == m) v = cur[m];
                        recBuf[myP[k]][s2] = v;
                    }
                }
            }
        }
        bnd[pw][2*w  ][col] = cur[0];
        bnd[pw][2*w+1][col] = cur[7];

        if ((t & 7) == 7) {
            const int o = t >> 3;
            if (t < NT-1) {
                // frame stores straight from registers (before the drain sync)
                unsigned long long* Fw = F[o & 1];
                const bool colF = (col >= HALO   && col < REGN-HALO);
                const bool colM = (col >= 2*HALO && col < REGN-2*HALO);
                #pragma unroll
                for (int m = 0; m < 8; ++m) {
                    const int i = r0 + m;
                    const bool rowF = (i >= HALO   && i < REGN-HALO);
                    const bool rowM = (i >= 2*HALO && i < REGN-2*HALO);
                    if (colF && rowF && !(colM && rowM))
                        stg2(&Fw[(size_t)b*NZX + (size_t)(oz+i)*NX + gx],
                             cur[m], prv[m]);
                }
                __syncthreads();  // per-wave vmcnt(0) drains + recBuf visible
                if (tid < 64) {   // wave 0: arrive + hard-spin on <=8 neighbors
                    if (tid == 0)
                        __hip_atomic_store(&flags[blk * FSTRIDE], (unsigned)(o+1),
                                           __ATOMIC_RELAXED, __HIP_MEMORY_SCOPE_AGENT);
                    for (;;) {
                        unsigned f = __hip_atomic_load(&flags[nbId * FSTRIDE],
                                         __ATOMIC_RELAXED, __HIP_MEMORY_SCOPE_AGENT);
                        if (__all(f >= (unsigned)(o+1))) break;
                    }
                } else {          // waves 1..7: flush y concurrently with poll
                    for (int k = tid - 64; k < recCnt*8; k += NTHR - 64) {
                        int p = k >> 3, s2 = k & 7;
                        y[(size_t)((o<<3)+s2)*(BB*NREC) + recOut[p]] = recBuf[p][s2];
                    }
                }
                __syncthreads();
                // ring read: issue ALL loads, then use (single waitcnt)
                const bool colH = (col < HALO || col >= REGN-HALO);
                unsigned long long tmp[8];
                bool ringm[8], valm[8];
                #pragma unroll
                for (int m = 0; m < 8; ++m) {
                    const int i = r0 + m;
                    const int gz = oz + i;
                    ringm[m] = colH || i < HALO || i >= REGN-HALO;
                    valm[m]  = gxIn && gz >= 0 && gz < NZ;
                    const int gzc = min(max(gz, 0), NZ-1);
                    if (ringm[m])
                        tmp[m] = ldg2(&Fw[(size_t)b*NZX + (size_t)gzc*NX + gxc]);
                }
                #pragma unroll
                for (int m = 0; m < 8; ++m) {
                    if (ringm[m]) {
                        cur[m] = valm[m] ? __uint_as_float((unsigned)tmp[m]) : 0.f;
                        prv[m] = valm[m] ? __uint_as_float((unsigned)(tmp[m] >> 32)) : 0.f;
                    }
                }
                bnd[pw][2*w  ][col] = cur[0];
                bnd[pw][2*w+1][col] = cur[7];
            } else {
                // last window: just flush y (all threads)
                __syncthreads();
                for (int k = tid; k < recCnt*8; k += NTHR) {
                    int p = k >> 3, s2 = k & 7;
                    y[(size_t)((o<<3)+s2)*(BB*NREC) + recOut[p]] = recBuf[p][s2];
                }
            }
        }
        __syncthreads();
    }
}

extern "C" void kernel_launch(void* const* d_in, const int* in_sizes, int n_in,
                              void* d_out, int out_size, void* d_ws, size_t ws_size,
                              hipStream_t stream) {
    const float* x     = (const float*)d_in[0];
    const float* vp    = (const float*)d_in[1];
    const int*   src_y = (const int*)d_in[2];
    const int*   src_x = (const int*)d_in[3];
    const int*   rec_y = (const int*)d_in[4];
    const int*   rec_x = (const int*)d_in[5];
    float* y  = (float*)d_out;
    float* ws = (float*)d_ws;   // 2 ping-pong float2 frames (4*BNZX floats) + flags

    wave_init<<<(NBLK*FSTRIDE + 255)/256, 256, 0, stream>>>((unsigned*)(ws + 4*BNZX));
    wave_tiled<<<NBLK, NTHR, 0, stream>>>(ws, vp, x, src_y, src_x, rec_y, rec_x, y);
}